// Round 1
// baseline (279.802 us; speedup 1.0000x reference)
//
#include <hip/hip_runtime.h>
#include <hip/hip_bf16.h>

typedef float f32x4 __attribute__((ext_vector_type(4)));
typedef __bf16 bf16x8 __attribute__((ext_vector_type(8)));

#define NB 4        // batch
#define NQ 4096
#define NK 4096
#define DIM 512
#define KD 64

__device__ inline bf16x8 load_cvt8(const float* __restrict__ p) {
    float4 f0 = *(const float4*)p;
    float4 f1 = *(const float4*)(p + 4);
    bf16x8 r;
    r[0] = (__bf16)f0.x; r[1] = (__bf16)f0.y; r[2] = (__bf16)f0.z; r[3] = (__bf16)f0.w;
    r[4] = (__bf16)f1.x; r[5] = (__bf16)f1.y; r[6] = (__bf16)f1.z; r[7] = (__bf16)f1.w;
    return r;
}

// ---- Q projection: Qb[b*NQ+q][kd] = sum_d x[row][d] * Wq[kd][d] + bq[kd]  (bf16 out)
__global__ __launch_bounds__(256) void proj_q_kernel(
        const float* __restrict__ x, const float* __restrict__ W,
        const float* __restrict__ bias, __bf16* __restrict__ out) {
    const int tid = threadIdx.x;
    const int w = tid >> 6, l = tid & 63;
    const int lr = l & 15, lk = l >> 4;
    const long rowbase = (long)blockIdx.x * 128 + w * 32;

    f32x4 acc[2][4] = {};
    for (int kk = 0; kk < DIM; kk += 32) {
        bf16x8 a0 = load_cvt8(x + (rowbase + lr) * DIM + kk + lk * 8);
        bf16x8 a1 = load_cvt8(x + (rowbase + 16 + lr) * DIM + kk + lk * 8);
        bf16x8 bw[4];
#pragma unroll
        for (int nb = 0; nb < 4; nb++)
            bw[nb] = load_cvt8(W + (long)(nb * 16 + lr) * DIM + kk + lk * 8);
#pragma unroll
        for (int nb = 0; nb < 4; nb++) {
            acc[0][nb] = __builtin_amdgcn_mfma_f32_16x16x32_bf16(a0, bw[nb], acc[0][nb], 0, 0, 0);
            acc[1][nb] = __builtin_amdgcn_mfma_f32_16x16x32_bf16(a1, bw[nb], acc[1][nb], 0, 0, 0);
        }
    }
#pragma unroll
    for (int nb = 0; nb < 4; nb++) {
        const int col = nb * 16 + lr;
        const float bs = bias[col];
#pragma unroll
        for (int mi = 0; mi < 2; mi++)
#pragma unroll
            for (int i = 0; i < 4; i++) {
                long row = rowbase + mi * 16 + lk * 4 + i;
                out[row * KD + col] = (__bf16)(acc[mi][nb][i] + bs);
            }
    }
}

// ---- fused K/V projection. Kb row-major [B*NK][KD]; Vt transposed [B][KD][NK].
__global__ __launch_bounds__(256) void proj_kv_kernel(
        const float* __restrict__ buf,
        const float* __restrict__ Wk, const float* __restrict__ bk,
        const float* __restrict__ Wv, const float* __restrict__ bv,
        __bf16* __restrict__ Kb, __bf16* __restrict__ Vt) {
    const int tid = threadIdx.x;
    const int w = tid >> 6, l = tid & 63;
    const int lr = l & 15, lk = l >> 4;
    const long rowbase = (long)blockIdx.x * 128 + w * 32;

    f32x4 acck[2][4] = {};
    f32x4 accv[2][4] = {};
    for (int kk = 0; kk < DIM; kk += 32) {
        bf16x8 a0 = load_cvt8(buf + (rowbase + lr) * DIM + kk + lk * 8);
        bf16x8 a1 = load_cvt8(buf + (rowbase + 16 + lr) * DIM + kk + lk * 8);
        bf16x8 bwk[4], bwv[4];
#pragma unroll
        for (int nb = 0; nb < 4; nb++) {
            bwk[nb] = load_cvt8(Wk + (long)(nb * 16 + lr) * DIM + kk + lk * 8);
            bwv[nb] = load_cvt8(Wv + (long)(nb * 16 + lr) * DIM + kk + lk * 8);
        }
#pragma unroll
        for (int nb = 0; nb < 4; nb++) {
            acck[0][nb] = __builtin_amdgcn_mfma_f32_16x16x32_bf16(a0, bwk[nb], acck[0][nb], 0, 0, 0);
            acck[1][nb] = __builtin_amdgcn_mfma_f32_16x16x32_bf16(a1, bwk[nb], acck[1][nb], 0, 0, 0);
            accv[0][nb] = __builtin_amdgcn_mfma_f32_16x16x32_bf16(a0, bwv[nb], accv[0][nb], 0, 0, 0);
            accv[1][nb] = __builtin_amdgcn_mfma_f32_16x16x32_bf16(a1, bwv[nb], accv[1][nb], 0, 0, 0);
        }
    }
#pragma unroll
    for (int nb = 0; nb < 4; nb++) {
        const int col = nb * 16 + lr;
        const float bsk = bk[col];
        const float bsv = bv[col];
#pragma unroll
        for (int mi = 0; mi < 2; mi++)
#pragma unroll
            for (int i = 0; i < 4; i++) {
                long row = rowbase + mi * 16 + lk * 4 + i;   // global key row in [0, B*NK)
                Kb[row * KD + col] = (__bf16)(acck[mi][nb][i] + bsk);
                int bidx = (int)(row >> 12);                 // row / 4096
                int kidx = (int)(row & 4095);
                Vt[((long)bidx * KD + col) * NK + kidx] = (__bf16)(accv[mi][nb][i] + bsv);
            }
    }
}

// ---- flash attention. One block = 64 q rows of one batch; wave w owns 16 rows.
__global__ __launch_bounds__(256) void attn_kernel(
        const __bf16* __restrict__ Qb, const __bf16* __restrict__ Kb,
        const __bf16* __restrict__ Vt, const int* __restrict__ mask,
        float* __restrict__ out) {
    __shared__ __bf16 plds[4][16][72];   // per-wave 16x64 P tile, padded to 72 (144B rows, 16B aligned)

    const int tid = threadIdx.x;
    const int w = tid >> 6, l = tid & 63;
    const int lr = l & 15, lk = l >> 4;
    const int b = blockIdx.x >> 6;
    const int q0 = (blockIdx.x & 63) * 64 + w * 16;

    const __bf16* Qp = Qb + ((long)b * NQ + q0) * KD;
    const __bf16* Kp = Kb + (long)b * NK * KD;
    const __bf16* Vp = Vt + (long)b * KD * NK;
    const int*    mp = mask + ((long)b * NQ + q0) * NK;

    bf16x8 qa[2];
#pragma unroll
    for (int ks = 0; ks < 2; ks++)
        qa[ks] = *(const bf16x8*)(Qp + (long)lr * KD + ks * 32 + lk * 8);

    f32x4 o[4] = {};
    float m_i[4], l_i[4];
#pragma unroll
    for (int i = 0; i < 4; i++) { m_i[i] = -INFINITY; l_i[i] = 0.f; }

    for (int kt = 0; kt < NK; kt += 64) {
        // ---- S = Q K^T  (16 q x 64 k)
        f32x4 s[4] = {};
#pragma unroll
        for (int ks = 0; ks < 2; ks++)
#pragma unroll
            for (int nb = 0; nb < 4; nb++) {
                bf16x8 kb = *(const bf16x8*)(Kp + (long)(kt + nb * 16 + lr) * KD + ks * 32 + lk * 8);
                s[nb] = __builtin_amdgcn_mfma_f32_16x16x32_bf16(qa[ks], kb, s[nb], 0, 0, 0);
            }
        // ---- scale + mask (C layout: row = lk*4+i, col = nb*16+lr)
#pragma unroll
        for (int nb = 0; nb < 4; nb++)
#pragma unroll
            for (int i = 0; i < 4; i++) {
                int mv = mp[(long)(lk * 4 + i) * NK + kt + nb * 16 + lr];
                s[nb][i] = mv ? s[nb][i] * 0.125f : -1024.0f;
            }
        // ---- online softmax, per row i
#pragma unroll
        for (int i = 0; i < 4; i++) {
            float v = fmaxf(fmaxf(s[0][i], s[1][i]), fmaxf(s[2][i], s[3][i]));
            v = fmaxf(v, __shfl_xor(v, 1));
            v = fmaxf(v, __shfl_xor(v, 2));
            v = fmaxf(v, __shfl_xor(v, 4));
            v = fmaxf(v, __shfl_xor(v, 8));
            float mnew = fmaxf(m_i[i], v);
            float sc = __expf(m_i[i] - mnew);
            m_i[i] = mnew;
            float rs = 0.f;
#pragma unroll
            for (int nb = 0; nb < 4; nb++) {
                float p = __expf(s[nb][i] - mnew);
                s[nb][i] = p;
                rs += p;
            }
            rs += __shfl_xor(rs, 1);
            rs += __shfl_xor(rs, 2);
            rs += __shfl_xor(rs, 4);
            rs += __shfl_xor(rs, 8);
            l_i[i] = l_i[i] * sc + rs;
#pragma unroll
            for (int nb = 0; nb < 4; nb++) o[nb][i] *= sc;
        }
        // ---- P -> LDS (bf16), intra-wave transpose
#pragma unroll
        for (int nb = 0; nb < 4; nb++)
#pragma unroll
            for (int i = 0; i < 4; i++)
                plds[w][lk * 4 + i][nb * 16 + lr] = (__bf16)s[nb][i];
        // ---- O += P V   (A = P from LDS, B = Vt rows, contiguous)
#pragma unroll
        for (int ks = 0; ks < 2; ks++) {
            bf16x8 pa = *(const bf16x8*)&plds[w][lr][ks * 32 + lk * 8];
#pragma unroll
            for (int nb = 0; nb < 4; nb++) {
                bf16x8 vb = *(const bf16x8*)(Vp + (long)(nb * 16 + lr) * NK + kt + ks * 32 + lk * 8);
                o[nb] = __builtin_amdgcn_mfma_f32_16x16x32_bf16(pa, vb, o[nb], 0, 0, 0);
            }
        }
    }
    // ---- epilogue: divide by softmax denom, write f32
#pragma unroll
    for (int nb = 0; nb < 4; nb++)
#pragma unroll
        for (int i = 0; i < 4; i++) {
            long row = (long)b * NQ + q0 + lk * 4 + i;
            out[row * KD + nb * 16 + lr] = o[nb][i] / l_i[i];
        }
}

extern "C" void kernel_launch(void* const* d_in, const int* in_sizes, int n_in,
                              void* d_out, int out_size, void* d_ws, size_t ws_size,
                              hipStream_t stream) {
    const float* x      = (const float*)d_in[0];
    const float* buffer = (const float*)d_in[1];
    const int*   mask   = (const int*)d_in[2];
    const float* Wq     = (const float*)d_in[3];
    const float* bq     = (const float*)d_in[4];
    const float* Wk     = (const float*)d_in[5];
    const float* bk     = (const float*)d_in[6];
    const float* Wv     = (const float*)d_in[7];
    const float* bv     = (const float*)d_in[8];
    float* out = (float*)d_out;

    __bf16* Qb = (__bf16*)d_ws;
    __bf16* Kb = Qb + (size_t)NB * NQ * KD;
    __bf16* Vt = Kb + (size_t)NB * NK * KD;

    proj_q_kernel<<<dim3((NB * NQ) / 128), dim3(256), 0, stream>>>(x, Wq, bq, Qb);
    proj_kv_kernel<<<dim3((NB * NK) / 128), dim3(256), 0, stream>>>(buffer, Wk, bk, Wv, bv, Kb, Vt);
    attn_kernel<<<dim3(NB * (NQ / 64)), dim3(256), 0, stream>>>(Qb, Kb, Vt, mask, out);
}